// Round 1
// baseline (41.333 us; speedup 1.0000x reference)
//
#include <hip/hip_runtime.h>

// Pool4d: x [b=2, c=8, l=16, d=32, h=64, w=64] f32
// kernel (3,3,3,3), stride (1,2,2,2), VALID, divide by 81.
// out [2, 8, 14, 15, 31, 31] f32.

#define BC   16          // b*c
#define L_IN 16
#define D_IN 32
#define H_IN 64
#define W_IN 64
#define L_O  14
#define D_O  15
#define H_O  31
#define W_O  31
#define SP_OUT (D_O * H_O * W_O)     // 14415
#define SP_IN  (D_IN * H_IN * W_IN)  // 131072

// Pass 1: per-frame 3x3x3 stride-2 spatial pool, raw sums.
// tmp layout: [BC, L_IN, D_O, H_O, W_O]
__global__ void pool_spatial(const float* __restrict__ x, float* __restrict__ tmp) {
    int idx = blockIdx.x * blockDim.x + threadIdx.x;
    const int total = BC * L_IN * SP_OUT;   // 3,690,240
    if (idx >= total) return;
    int wo  = idx % W_O;
    int t   = idx / W_O;
    int ho  = t % H_O;
    t      /= H_O;
    int dd  = t % D_O;
    int bcl = t / D_O;                      // bc*L_IN + l fused
    const float* base = x + (size_t)bcl * SP_IN
                          + (size_t)(2 * dd) * (H_IN * W_IN)
                          + (2 * ho) * W_IN + 2 * wo;
    float s = 0.0f;
    #pragma unroll
    for (int kd = 0; kd < 3; ++kd) {
        #pragma unroll
        for (int kh = 0; kh < 3; ++kh) {
            const float* p = base + kd * (H_IN * W_IN) + kh * W_IN;
            s += p[0] + p[1] + p[2];
        }
    }
    tmp[idx] = s;
}

// Pass 2: temporal sliding window (k=3, stride=1) + scale by 1/81.
__global__ void pool_temporal(const float* __restrict__ tmp, float* __restrict__ out) {
    int idx = blockIdx.x * blockDim.x + threadIdx.x;
    const int total = BC * SP_OUT;          // 230,640
    if (idx >= total) return;
    int sp = idx % SP_OUT;
    int bc = idx / SP_OUT;
    const float* tp = tmp + (size_t)bc * L_IN * SP_OUT + sp;
    float v[L_IN];
    #pragma unroll
    for (int l = 0; l < L_IN; ++l) v[l] = tp[(size_t)l * SP_OUT];
    float* op = out + (size_t)bc * L_O * SP_OUT + sp;
    const float inv = 1.0f / 81.0f;
    #pragma unroll
    for (int lo = 0; lo < L_O; ++lo)
        op[(size_t)lo * SP_OUT] = (v[lo] + v[lo + 1] + v[lo + 2]) * inv;
}

// Fallback: direct one-pass (used only if workspace is too small).
__global__ void pool_direct(const float* __restrict__ x, float* __restrict__ out) {
    int idx = blockIdx.x * blockDim.x + threadIdx.x;
    const int total = BC * L_O * SP_OUT;    // 3,228,960
    if (idx >= total) return;
    int wo = idx % W_O;
    int t  = idx / W_O;
    int ho = t % H_O;
    t     /= H_O;
    int dd = t % D_O;
    t     /= D_O;
    int lo = t % L_O;
    int bc = t / L_O;
    const float* base = x + ((size_t)bc * L_IN + lo) * SP_IN
                          + (size_t)(2 * dd) * (H_IN * W_IN)
                          + (2 * ho) * W_IN + 2 * wo;
    float s = 0.0f;
    for (int kl = 0; kl < 3; ++kl) {
        const float* fb = base + (size_t)kl * SP_IN;
        #pragma unroll
        for (int kd = 0; kd < 3; ++kd) {
            #pragma unroll
            for (int kh = 0; kh < 3; ++kh) {
                const float* p = fb + kd * (H_IN * W_IN) + kh * W_IN;
                s += p[0] + p[1] + p[2];
            }
        }
    }
    out[idx] = s * (1.0f / 81.0f);
}

extern "C" void kernel_launch(void* const* d_in, const int* in_sizes, int n_in,
                              void* d_out, int out_size, void* d_ws, size_t ws_size,
                              hipStream_t stream) {
    const float* x = (const float*)d_in[0];
    float* out = (float*)d_out;

    const size_t tmp_bytes = (size_t)BC * L_IN * SP_OUT * sizeof(float); // ~14.1 MiB
    if (ws_size >= tmp_bytes) {
        float* tmp = (float*)d_ws;
        {
            int total = BC * L_IN * SP_OUT;
            int block = 256;
            int grid = (total + block - 1) / block;
            pool_spatial<<<grid, block, 0, stream>>>(x, tmp);
        }
        {
            int total = BC * SP_OUT;
            int block = 256;
            int grid = (total + block - 1) / block;
            pool_temporal<<<grid, block, 0, stream>>>(tmp, out);
        }
    } else {
        int total = BC * L_O * SP_OUT;
        int block = 256;
        int grid = (total + block - 1) / block;
        pool_direct<<<grid, block, 0, stream>>>(x, out);
    }
}

// Round 2
// 36.058 us; speedup vs baseline: 1.1463x; 1.1463x over previous
//
#include <hip/hip_runtime.h>

// Pool4d: x [b=2, c=8, l=16, d=32, h=64, w=64] f32
// kernel (3,3,3,3), stride (1,2,2,2), VALID, divide by 81.
// out [2, 8, 14, 15, 31, 31] f32.
//
// Fused single-pass: one thread per output spatial site; loops all 16
// l-frames computing 3x3x3 spatial sums into registers, then emits the 14
// temporal sliding-window outputs. No workspace traffic.

#define BC   16          // b*c
#define L_IN 16
#define D_IN 32
#define H_IN 64
#define W_IN 64
#define L_O  14
#define D_O  15
#define H_O  31
#define W_O  31
#define SP_OUT (D_O * H_O * W_O)     // 14415
#define SP_IN  (D_IN * H_IN * W_IN)  // 131072

__global__ void pool4d_fused(const float* __restrict__ x, float* __restrict__ out) {
    int idx = blockIdx.x * blockDim.x + threadIdx.x;
    const int total = BC * SP_OUT;          // 230,640
    if (idx >= total) return;
    int wo = idx % W_O;
    int t  = idx / W_O;
    int ho = t % H_O;
    t     /= H_O;
    int dd = t % D_O;
    int bc = t / D_O;

    const float* xb = x + (size_t)bc * L_IN * SP_IN
                        + (size_t)(2 * dd) * (H_IN * W_IN)
                        + (2 * ho) * W_IN + 2 * wo;

    // Spatial 3x3x3 sums for all 16 frames (fully unrolled -> static indexing).
    float s[L_IN];
    #pragma unroll
    for (int l = 0; l < L_IN; ++l) {
        const float* fb = xb + (size_t)l * SP_IN;
        float acc = 0.0f;
        #pragma unroll
        for (int kd = 0; kd < 3; ++kd) {
            #pragma unroll
            for (int kh = 0; kh < 3; ++kh) {
                const float* p = fb + kd * (H_IN * W_IN) + kh * W_IN;
                acc += p[0] + p[1] + p[2];
            }
        }
        s[l] = acc;
    }

    // Temporal sliding window (k=3, stride=1) + scale.
    int sp = (dd * H_O + ho) * W_O + wo;
    float* op = out + (size_t)bc * L_O * SP_OUT + sp;
    const float inv = 1.0f / 81.0f;
    #pragma unroll
    for (int lo = 0; lo < L_O; ++lo)
        op[(size_t)lo * SP_OUT] = (s[lo] + s[lo + 1] + s[lo + 2]) * inv;
}

extern "C" void kernel_launch(void* const* d_in, const int* in_sizes, int n_in,
                              void* d_out, int out_size, void* d_ws, size_t ws_size,
                              hipStream_t stream) {
    const float* x = (const float*)d_in[0];
    float* out = (float*)d_out;
    (void)d_ws; (void)ws_size;

    int total = BC * SP_OUT;
    int block = 256;
    int grid = (total + block - 1) / block;
    pool4d_fused<<<grid, block, 0, stream>>>(x, out);
}